// Round 1
// baseline (49553.354 us; speedup 1.0000x reference)
//
#include <hip/hip_runtime.h>
#include <math.h>

#define BB 512
#define HH 400
#define DD 40
#define BM 64
#define BN 32
#define KS 16
#define NKC 25   // 400 / 16
#define NTHR 256
#define TT 200
#define NC 12

struct Wts {
  const float *Wh0,*bh0,*Wz0,*bz0,*Wr0,*br0,*Uh0,*Uz0,*Ur0;
  const float *Wh1,*bh1,*Wz1,*bz1,*Wr1,*br1,*Uh1,*Uz1,*Ur1;
};
struct Scr {
  float *rt0,*zt0,*atmp0,*pr1,*pz1,*rt1,*zt1,*wh1p;
};

__device__ __forceinline__ float sigq(float x) {
  float v = rintf(x * 12.4f) / 31.0f;           // round-half-even like jnp.round
  return fminf(fmaxf(v, 0.0f), 1.0f);
}
__device__ __forceinline__ float tanhq(float x) {
  float v = rintf(x * 31.0f) / 31.0f;
  return fminf(fmaxf(v, -1.0f), 1.0f);
}

// One kernel handles all 4 dependency phases of a timestep (uniform branches).
// out[b,j] = epilogue( sum_k A[b,k]*W[j,k] (+ sum_k40 x[b,k]*W2[j,k]) )
__global__ __launch_bounds__(NTHR) void gru_phase(
    Wts w, Scr s, const float* __restrict__ x_t,
    const float* __restrict__ h0c, float* __restrict__ h0n,
    const float* __restrict__ h1c, float* __restrict__ h1n,
    int phase)
{
  const int tid = threadIdx.x;
  const int b0 = blockIdx.x * BM;
  const int j0 = blockIdx.y * BN;
  const int z  = blockIdx.z;

  const float* A = nullptr; const float* W = nullptr; const float* W2 = nullptr;
  const float* bias = nullptr; const float* ebuf = nullptr;
  float* out = nullptr;
  int amode = 0, epi = 0;       // amode: 0 plain A, 1 rt0*h0c, 2 h0n on-the-fly, 3 rt1*h1c
  bool writeH0 = false;

  if (phase == 1) {
    if (z == 0)      { A=h0c; W=w.Ur0; bias=w.br0; W2=w.Wr0; out=s.rt0; epi=1; }
    else if (z == 1) { A=h1c; W=w.Ur1; bias=w.br1;           out=s.pr1; epi=0; }
    else             { A=h1c; W=w.Uz1; bias=w.bz1;           out=s.pz1; epi=0; }
  } else if (phase == 2) {
    if (z == 0)      { A=h0c; W=w.Uz0; bias=w.bz0; W2=w.Wz0; out=s.zt0;   epi=1; }
    else             { amode=1; W=w.Uh0; bias=w.bh0; W2=w.Wh0; out=s.atmp0; epi=0; }
  } else if (phase == 3) {
    amode = 2;
    writeH0 = (z == 0) && (blockIdx.y == 0);
    if (z == 0)      { W=w.Wr1; ebuf=s.pr1; out=s.rt1;  epi=2; }
    else if (z == 1) { W=w.Wz1; ebuf=s.pz1; out=s.zt1;  epi=2; }
    else             { W=w.Wh1; bias=w.bh1; out=s.wh1p; epi=0; }
  } else { // phase 4
    amode=3; W=w.Uh1; out=h1n; epi=4;
  }

  __shared__ float As[KS][BM+1];
  __shared__ float Ws[KS][BN+1];
  __shared__ float Xs[DD][BM+1];
  __shared__ float W2s[DD][BN+1];

  float acc[4][2] = {};

  const int tx = tid & 15;   // N dir: cols tx*2, tx*2+1
  const int ty = tid >> 4;   // M dir: rows ty*4 .. ty*4+3

  // ---- K=40 input-projection part (x_t @ W2^T), only phases that need it ----
  if (W2) {
    for (int idx = tid; idx < BM*DD; idx += NTHR)
      Xs[idx % DD][idx / DD] = x_t[b0*DD + idx];               // coalesced
    for (int idx = tid; idx < BN*DD; idx += NTHR) {
      int j = idx / DD, k = idx % DD;
      W2s[k][j] = (j0 + j < HH) ? W2[(j0+j)*DD + k] : 0.0f;
    }
    __syncthreads();
    #pragma unroll
    for (int k = 0; k < DD; ++k) {
      float a0 = Xs[k][ty*4+0], a1 = Xs[k][ty*4+1], a2 = Xs[k][ty*4+2], a3 = Xs[k][ty*4+3];
      float w0 = W2s[k][tx*2+0], w1 = W2s[k][tx*2+1];
      acc[0][0] += a0*w0; acc[0][1] += a0*w1;
      acc[1][0] += a1*w0; acc[1][1] += a1*w1;
      acc[2][0] += a2*w0; acc[2][1] += a2*w1;
      acc[3][0] += a3*w0; acc[3][1] += a3*w1;
    }
  }

  // ---- main K=400 loop ----
  const int ks = tid & 15;   // k within chunk (staging)
  const int rs = tid >> 4;   // row index (staging)

  for (int kc = 0; kc < NKC; ++kc) {
    const int k0 = kc * KS;
    __syncthreads();
    // stage A tile (transposed): As[k][b]
    #pragma unroll
    for (int it = 0; it < 4; ++it) {
      int b  = b0 + rs + it*16;
      int gk = k0 + ks;
      float v;
      if      (amode == 0) v = A[b*HH + gk];
      else if (amode == 1) v = s.rt0[b*HH+gk] * h0c[b*HH+gk];
      else if (amode == 3) v = s.rt1[b*HH+gk] * h1c[b*HH+gk];
      else { // amode 2: h0' = zt0*h0 + (1-zt0)*tanhq(atmp0)
        float zv = s.zt0[b*HH+gk];
        float hv = h0c[b*HH+gk];
        float hc = tanhq(s.atmp0[b*HH+gk]);
        v = zv*hv + (1.0f - zv)*hc;
        if (writeH0) h0n[b*HH+gk] = v;   // materialize h0' once for next phases/steps
      }
      As[ks][rs + it*16] = v;
    }
    // stage W tile (transposed): Ws[k][j]
    #pragma unroll
    for (int it = 0; it < 2; ++it) {
      int jj = j0 + rs + it*16;
      Ws[ks][rs + it*16] = (jj < HH) ? W[jj*HH + k0 + ks] : 0.0f;
    }
    __syncthreads();
    #pragma unroll
    for (int k = 0; k < KS; ++k) {
      float a0 = As[k][ty*4+0], a1 = As[k][ty*4+1], a2 = As[k][ty*4+2], a3 = As[k][ty*4+3];
      float w0 = Ws[k][tx*2+0], w1 = Ws[k][tx*2+1];
      acc[0][0] += a0*w0; acc[0][1] += a0*w1;
      acc[1][0] += a1*w0; acc[1][1] += a1*w1;
      acc[2][0] += a2*w0; acc[2][1] += a2*w1;
      acc[3][0] += a3*w0; acc[3][1] += a3*w1;
    }
  }

  // ---- epilogue ----
  #pragma unroll
  for (int m = 0; m < 4; ++m) {
    int b = b0 + ty*4 + m;
    #pragma unroll
    for (int n = 0; n < 2; ++n) {
      int j = j0 + tx*2 + n;
      if (j < HH) {
        float v = acc[m][n];
        float r;
        if      (epi == 0) r = v + bias[j];
        else if (epi == 1) r = sigq(v + bias[j]);
        else if (epi == 2) r = sigq(v + ebuf[b*HH+j]);
        else { // epi 4: final layer-1 combine
          float av = v + s.wh1p[b*HH+j];
          float hc = tanhq(av);
          float zv = s.zt1[b*HH+j];
          float hv = h1c[b*HH+j];
          r = zv*hv + (1.0f - zv)*hc;
        }
        out[b*HH + j] = r;
      }
    }
  }
}

// out = softmax(h1 @ Wfc^T + bfc), one wave per batch row
__global__ __launch_bounds__(64) void fc_softmax(
    const float* __restrict__ h1, const float* __restrict__ Wfc,
    const float* __restrict__ bfc, float* __restrict__ out)
{
  const int b = blockIdx.x;
  const int lane = threadIdx.x;
  float l[NC];
  #pragma unroll
  for (int c = 0; c < NC; ++c) {
    float sm = 0.0f;
    for (int k = lane; k < HH; k += 64)
      sm += h1[b*HH + k] * Wfc[c*HH + k];
    #pragma unroll
    for (int off = 32; off > 0; off >>= 1)
      sm += __shfl_xor(sm, off);
    l[c] = sm + bfc[c];
  }
  float mx = l[0];
  #pragma unroll
  for (int c = 1; c < NC; ++c) mx = fmaxf(mx, l[c]);
  float sum = 0.0f;
  #pragma unroll
  for (int c = 0; c < NC; ++c) { l[c] = expf(l[c] - mx); sum += l[c]; }
  float inv = 1.0f / sum;
  if (lane == 0) {
    #pragma unroll
    for (int c = 0; c < NC; ++c) out[b*NC + c] = l[c] * inv;
  }
}

extern "C" void kernel_launch(void* const* d_in, const int* in_sizes, int n_in,
                              void* d_out, int out_size, void* d_ws, size_t ws_size,
                              hipStream_t stream) {
  const float* x = (const float*)d_in[0];
  Wts w;
  w.Wh0=(const float*)d_in[1];  w.bh0=(const float*)d_in[2];
  w.Wz0=(const float*)d_in[3];  w.bz0=(const float*)d_in[4];
  w.Wr0=(const float*)d_in[5];  w.br0=(const float*)d_in[6];
  w.Uh0=(const float*)d_in[7];  w.Uz0=(const float*)d_in[8];  w.Ur0=(const float*)d_in[9];
  w.Wh1=(const float*)d_in[10]; w.bh1=(const float*)d_in[11];
  w.Wz1=(const float*)d_in[12]; w.bz1=(const float*)d_in[13];
  w.Wr1=(const float*)d_in[14]; w.br1=(const float*)d_in[15];
  w.Uh1=(const float*)d_in[16]; w.Uz1=(const float*)d_in[17]; w.Ur1=(const float*)d_in[18];
  const float* Wfc = (const float*)d_in[19];
  const float* bfc = (const float*)d_in[20];

  float* ws = (float*)d_ws;
  const size_t SZ = (size_t)BB * HH;   // 204800 floats
  float* h0buf[2] = { ws + 0*SZ, ws + 1*SZ };
  float* h1buf[2] = { ws + 2*SZ, ws + 3*SZ };
  Scr s;
  s.rt0   = ws + 4*SZ;  s.zt0  = ws + 5*SZ;  s.atmp0 = ws + 6*SZ;
  s.pr1   = ws + 7*SZ;  s.pz1  = ws + 8*SZ;
  s.rt1   = ws + 9*SZ;  s.zt1  = ws + 10*SZ; s.wh1p  = ws + 11*SZ;

  hipMemsetAsync(h0buf[0], 0, SZ*sizeof(float), stream);
  hipMemsetAsync(h1buf[0], 0, SZ*sizeof(float), stream);

  dim3 blk(NTHR);
  for (int t = 0; t < TT; ++t) {
    const float* x_t = x + (size_t)t * BB * DD;
    const float* h0c = h0buf[t & 1];
    float*       h0n = h0buf[(t + 1) & 1];
    const float* h1c = h1buf[t & 1];
    float*       h1n = h1buf[(t + 1) & 1];
    gru_phase<<<dim3(8,13,3), blk, 0, stream>>>(w, s, x_t, h0c, h0n, h1c, h1n, 1);
    gru_phase<<<dim3(8,13,2), blk, 0, stream>>>(w, s, x_t, h0c, h0n, h1c, h1n, 2);
    gru_phase<<<dim3(8,13,3), blk, 0, stream>>>(w, s, x_t, h0c, h0n, h1c, h1n, 3);
    gru_phase<<<dim3(8,13,1), blk, 0, stream>>>(w, s, x_t, h0c, h0n, h1c, h1n, 4);
  }
  // final hidden of layer 1 is in h1buf[(TT) & 1] == h1buf[0]
  fc_softmax<<<dim3(BB), dim3(64), 0, stream>>>(h1buf[0], Wfc, bfc, (float*)d_out);
}

// Round 3
// 49266.083 us; speedup vs baseline: 1.0058x; 1.0058x over previous
//
#include <hip/hip_runtime.h>
#include <hip/hip_cooperative_groups.h>
#include <math.h>

namespace cg = cooperative_groups;

#define TT 200
#define BB 512
#define DD 40
#define HH 400
#define NC 12
#define GBLK 256
#define NTHR 256
#define NB_BETA 520
#define NB_ALPHA 208
#define NB_PRO 104
#define NB_FC 128

struct P {
  const float *x;
  const float *Wh0,*bh0,*Wz0,*bz0,*Wr0,*br0,*Uh0,*Uz0,*Ur0;
  const float *Wh1,*bh1,*Wz1,*bz1,*Wr1,*br1,*Uh1,*Uz1,*Ur1;
  const float *Wfc,*bfc;
  float *h0a,*h0b,*h1a,*h1b;          // ping-pong states
  float *rt1,*zt1,*ah1p,*rt0n,*zt0n;  // per-step gate buffers
  float *out;
};

__device__ __forceinline__ float sigq(float x){
  float v = rintf(x * 12.4f) / 31.0f;
  return fminf(fmaxf(v, 0.0f), 1.0f);
}
__device__ __forceinline__ float tanhq(float x){
  float v = rintf(x * 31.0f) / 31.0f;
  return fminf(fmaxf(v, -1.0f), 1.0f);
}

// acc[i][j] += sum_k A[r0+i][k] * W[c0+j][k], K multiple of 4, rows 16B-aligned.
__device__ __forceinline__ void gacc(const float* __restrict__ A, int lda,
                                     const float* __restrict__ W, int ldw,
                                     int r0, int c0, int K, float acc[4][2])
{
  const float4* a0 = (const float4*)(A + (size_t)(r0+0)*lda);
  const float4* a1 = (const float4*)(A + (size_t)(r0+1)*lda);
  const float4* a2 = (const float4*)(A + (size_t)(r0+2)*lda);
  const float4* a3 = (const float4*)(A + (size_t)(r0+3)*lda);
  const float4* w0 = (const float4*)(W + (size_t)(c0+0)*ldw);
  const float4* w1 = (const float4*)(W + (size_t)(c0+1)*ldw);
  const int K4 = K >> 2;
  for (int k = 0; k < K4; ++k) {
    float4 wv0 = w0[k], wv1 = w1[k];
    float4 av;
    av = a0[k];
    acc[0][0] += av.x*wv0.x; acc[0][0] += av.y*wv0.y; acc[0][0] += av.z*wv0.z; acc[0][0] += av.w*wv0.w;
    acc[0][1] += av.x*wv1.x; acc[0][1] += av.y*wv1.y; acc[0][1] += av.z*wv1.z; acc[0][1] += av.w*wv1.w;
    av = a1[k];
    acc[1][0] += av.x*wv0.x; acc[1][0] += av.y*wv0.y; acc[1][0] += av.z*wv0.z; acc[1][0] += av.w*wv0.w;
    acc[1][1] += av.x*wv1.x; acc[1][1] += av.y*wv1.y; acc[1][1] += av.z*wv1.z; acc[1][1] += av.w*wv1.w;
    av = a2[k];
    acc[2][0] += av.x*wv0.x; acc[2][0] += av.y*wv0.y; acc[2][0] += av.z*wv0.z; acc[2][0] += av.w*wv0.w;
    acc[2][1] += av.x*wv1.x; acc[2][1] += av.y*wv1.y; acc[2][1] += av.z*wv1.z; acc[2][1] += av.w*wv1.w;
    av = a3[k];
    acc[3][0] += av.x*wv0.x; acc[3][0] += av.y*wv0.y; acc[3][0] += av.z*wv0.z; acc[3][0] += av.w*wv0.w;
    acc[3][1] += av.x*wv1.x; acc[3][1] += av.y*wv1.y; acc[3][1] += av.z*wv1.z; acc[3][1] += av.w*wv1.w;
  }
}

// acc[i][j] += sum_k (Ap[r0+i][k]*Am[r0+i][k]) * W[c0+j][k]
__device__ __forceinline__ void pacc(const float* __restrict__ Ap, const float* __restrict__ Am,
                                     const float* __restrict__ W, int ldw,
                                     int r0, int c0, int K, float acc[4][2])
{
  const float4* w0 = (const float4*)(W + (size_t)(c0+0)*ldw);
  const float4* w1 = (const float4*)(W + (size_t)(c0+1)*ldw);
  const int K4 = K >> 2;
  for (int k = 0; k < K4; ++k) {
    float4 wv0 = w0[k], wv1 = w1[k];
    #pragma unroll
    for (int i = 0; i < 4; ++i) {
      float4 pv = ((const float4*)(Ap + (size_t)(r0+i)*HH))[k];
      float4 mv = ((const float4*)(Am + (size_t)(r0+i)*HH))[k];
      float4 av; av.x = pv.x*mv.x; av.y = pv.y*mv.y; av.z = pv.z*mv.z; av.w = pv.w*mv.w;
      acc[i][0] += av.x*wv0.x; acc[i][0] += av.y*wv0.y; acc[i][0] += av.z*wv0.z; acc[i][0] += av.w*wv0.w;
      acc[i][1] += av.x*wv1.x; acc[i][1] += av.y*wv1.y; acc[i][1] += av.z*wv1.z; acc[i][1] += av.w*wv1.w;
    }
  }
}

__device__ __forceinline__ void tile_of(int u, int& m, int& b0, int& j0){
  m = u / 104; int r = u % 104;
  b0 = (r / 13) * 64;
  j0 = (r % 13) * 32;
}

// beta(t): rt1, zt1, ah1p for step t; rt0n, zt0n for step t+1
__device__ void beta_unit(const P& p, int u, int t, int tid){
  int m, b0, j0; tile_of(u, m, b0, j0);
  const int tx = tid & 15, ty = tid >> 4;
  const int r0 = b0 + ty*4;
  const int c  = j0 + tx*2;
  const int c0 = c < 398 ? c : 398;
  const float* h0n = (t & 1) ? p.h0b : p.h0a;
  const float* h1c = (t & 1) ? p.h1b : p.h1a;
  const float* xt1 = p.x + (size_t)((t+1) % TT) * BB * DD;

  float acc[4][2] = {};
  const float* bias; float* out; int act = 1;
  if (m == 0)      { gacc(h1c,HH,p.Ur1,HH,r0,c0,HH,acc); gacc(h0n,HH,p.Wr1,HH,r0,c0,HH,acc); bias=p.br1; out=p.rt1; }
  else if (m == 1) { gacc(h1c,HH,p.Uz1,HH,r0,c0,HH,acc); gacc(h0n,HH,p.Wz1,HH,r0,c0,HH,acc); bias=p.bz1; out=p.zt1; }
  else if (m == 2) { gacc(h0n,HH,p.Wh1,HH,r0,c0,HH,acc); bias=p.bh1; out=p.ah1p; act=0; }
  else if (m == 3) { gacc(h0n,HH,p.Ur0,HH,r0,c0,HH,acc); gacc(xt1,DD,p.Wr0,DD,r0,c0,DD,acc); bias=p.br0; out=p.rt0n; }
  else             { gacc(h0n,HH,p.Uz0,HH,r0,c0,HH,acc); gacc(xt1,DD,p.Wz0,DD,r0,c0,DD,acc); bias=p.bz0; out=p.zt0n; }

  #pragma unroll
  for (int i = 0; i < 4; ++i) {
    #pragma unroll
    for (int j = 0; j < 2; ++j) {
      int cc = j0 + tx*2 + j;
      if (cc < HH) {
        float v = acc[i][j] + bias[cc];
        out[(size_t)(r0+i)*HH + cc] = act ? sigq(v) : v;
      }
    }
  }
}

// alpha(t): m=0 finishes layer-1 (writes h1(t)); m=1 layer-0 of step t+1 (writes h0(t+1))
__device__ void alpha_unit(const P& p, int u, int t, int tid){
  int m, b0, j0; tile_of(u, m, b0, j0);
  const int tx = tid & 15, ty = tid >> 4;
  const int r0 = b0 + ty*4;
  const int c  = j0 + tx*2;
  const int c0 = c < 398 ? c : 398;
  const float* h0n = (t & 1) ? p.h0b : p.h0a;
  const float* h1c = (t & 1) ? p.h1b : p.h1a;
  float* h0w = (t & 1) ? p.h0a : p.h0b;
  float* h1w = (t & 1) ? p.h1a : p.h1b;
  const float* xt1 = p.x + (size_t)((t+1) % TT) * BB * DD;

  float acc[4][2] = {};
  if (m == 0) {
    pacc(p.rt1, h1c, p.Uh1, HH, r0, c0, HH, acc);
    #pragma unroll
    for (int i = 0; i < 4; ++i)
      #pragma unroll
      for (int j = 0; j < 2; ++j) {
        int cc = j0 + tx*2 + j;
        if (cc < HH) {
          size_t idx = (size_t)(r0+i)*HH + cc;
          float at1 = acc[i][j] + p.ah1p[idx];
          float z = p.zt1[idx], hv = h1c[idx];
          h1w[idx] = z*hv + (1.0f - z)*tanhq(at1);
        }
      }
  } else {
    pacc(p.rt0n, h0n, p.Uh0, HH, r0, c0, HH, acc);
    gacc(xt1, DD, p.Wh0, DD, r0, c0, DD, acc);
    #pragma unroll
    for (int i = 0; i < 4; ++i)
      #pragma unroll
      for (int j = 0; j < 2; ++j) {
        int cc = j0 + tx*2 + j;
        if (cc < HH) {
          size_t idx = (size_t)(r0+i)*HH + cc;
          float at0 = acc[i][j] + p.bh0[cc];
          float z = p.zt0n[idx], hv = h0n[idx];
          h0w[idx] = z*hv + (1.0f - z)*tanhq(at0);
        }
      }
  }
}

// prologue: h0(0) = (1 - sigq(x0 Wz0^T + bz0)) * tanhq(x0 Wh0^T + bh0)
__device__ void pro_unit(const P& p, int u, int tid){
  int b0 = (u / 13) * 64, j0 = (u % 13) * 32;
  const int tx = tid & 15, ty = tid >> 4;
  const int r0 = b0 + ty*4;
  const int c  = j0 + tx*2;
  const int c0 = c < 398 ? c : 398;
  float accz[4][2] = {}, acca[4][2] = {};
  gacc(p.x, DD, p.Wz0, DD, r0, c0, DD, accz);
  gacc(p.x, DD, p.Wh0, DD, r0, c0, DD, acca);
  #pragma unroll
  for (int i = 0; i < 4; ++i)
    #pragma unroll
    for (int j = 0; j < 2; ++j) {
      int cc = j0 + tx*2 + j;
      if (cc < HH) {
        float z = sigq(accz[i][j] + p.bz0[cc]);
        float a = acca[i][j] + p.bh0[cc];
        p.h0a[(size_t)(r0+i)*HH + cc] = (1.0f - z)*tanhq(a);
      }
    }
}

__device__ void fc_unit(const P& p, int u, int tid){
  const int w = tid >> 6, lane = tid & 63;
  const int b = u*4 + w;
  const float* h1 = p.h1a;   // h1(199): t=199 odd -> written to h1a
  float l[NC];
  #pragma unroll
  for (int cI = 0; cI < NC; ++cI) {
    float sm = 0.0f;
    for (int k = lane; k < HH; k += 64)
      sm += h1[(size_t)b*HH + k] * p.Wfc[(size_t)cI*HH + k];
    #pragma unroll
    for (int off = 32; off > 0; off >>= 1)
      sm += __shfl_xor(sm, off);
    l[cI] = sm + p.bfc[cI];
  }
  float mx = l[0];
  #pragma unroll
  for (int cI = 1; cI < NC; ++cI) mx = fmaxf(mx, l[cI]);
  float sum = 0.0f;
  #pragma unroll
  for (int cI = 0; cI < NC; ++cI) { l[cI] = expf(l[cI] - mx); sum += l[cI]; }
  float inv = 1.0f / sum;
  if (lane == 0) {
    #pragma unroll
    for (int cI = 0; cI < NC; ++cI) p.out[(size_t)b*NC + cI] = l[cI] * inv;
  }
}

// ---- cooperative single-kernel path (256 blocks: one per CU, grid-stride) ----
__global__ __launch_bounds__(NTHR, 2) void gru_coop(P p){
  cg::grid_group grid = cg::this_grid();
  const int bid = blockIdx.x;
  const int tid = threadIdx.x;

  for (int u = bid; u < NB_PRO; u += GBLK) pro_unit(p, u, tid);
  grid.sync();
  for (int t = 0; t < TT; ++t) {
    for (int u = bid; u < NB_BETA; u += GBLK) beta_unit(p, u, t, tid);
    grid.sync();
    for (int u = bid; u < NB_ALPHA; u += GBLK) alpha_unit(p, u, t, tid);
    grid.sync();
  }
  for (int u = bid; u < NB_FC; u += GBLK) fc_unit(p, u, tid);
}

// ---- fallback regular-launch path (same device functions) ----
__global__ __launch_bounds__(NTHR) void k_pro(P p)         { pro_unit(p, blockIdx.x, threadIdx.x); }
__global__ __launch_bounds__(NTHR) void k_beta(P p, int t) { beta_unit(p, blockIdx.x, t, threadIdx.x); }
__global__ __launch_bounds__(NTHR) void k_alpha(P p, int t){ alpha_unit(p, blockIdx.x, t, threadIdx.x); }
__global__ __launch_bounds__(NTHR) void k_fc(P p)          { fc_unit(p, blockIdx.x, threadIdx.x); }

extern "C" void kernel_launch(void* const* d_in, const int* in_sizes, int n_in,
                              void* d_out, int out_size, void* d_ws, size_t ws_size,
                              hipStream_t stream) {
  P p;
  p.x   = (const float*)d_in[0];
  p.Wh0 = (const float*)d_in[1];  p.bh0 = (const float*)d_in[2];
  p.Wz0 = (const float*)d_in[3];  p.bz0 = (const float*)d_in[4];
  p.Wr0 = (const float*)d_in[5];  p.br0 = (const float*)d_in[6];
  p.Uh0 = (const float*)d_in[7];  p.Uz0 = (const float*)d_in[8];  p.Ur0 = (const float*)d_in[9];
  p.Wh1 = (const float*)d_in[10]; p.bh1 = (const float*)d_in[11];
  p.Wz1 = (const float*)d_in[12]; p.bz1 = (const float*)d_in[13];
  p.Wr1 = (const float*)d_in[14]; p.br1 = (const float*)d_in[15];
  p.Uh1 = (const float*)d_in[16]; p.Uz1 = (const float*)d_in[17]; p.Ur1 = (const float*)d_in[18];
  p.Wfc = (const float*)d_in[19]; p.bfc = (const float*)d_in[20];

  float* ws = (float*)d_ws;
  const size_t SZ = (size_t)BB * HH;
  p.h0a  = ws + 0*SZ;  p.h0b  = ws + 1*SZ;
  p.h1a  = ws + 2*SZ;  p.h1b  = ws + 3*SZ;
  p.rt1  = ws + 4*SZ;  p.zt1  = ws + 5*SZ;  p.ah1p = ws + 6*SZ;
  p.rt0n = ws + 7*SZ;  p.zt0n = ws + 8*SZ;
  p.out  = (float*)d_out;

  // h1(-1) = 0. Everything else is written before it is read.
  hipMemsetAsync(p.h1a, 0, SZ*sizeof(float), stream);

  void* args[] = { &p };
  hipError_t err = hipLaunchCooperativeKernel((const void*)gru_coop, dim3(GBLK),
                                              dim3(NTHR), args, 0, stream);
  if (err != hipSuccess) {
    // Deterministic fallback: identical math via regular launches.
    k_pro<<<dim3(NB_PRO), dim3(NTHR), 0, stream>>>(p);
    for (int t = 0; t < TT; ++t) {
      k_beta <<<dim3(NB_BETA),  dim3(NTHR), 0, stream>>>(p, t);
      k_alpha<<<dim3(NB_ALPHA), dim3(NTHR), 0, stream>>>(p, t);
    }
    k_fc<<<dim3(NB_FC), dim3(NTHR), 0, stream>>>(p);
  }
}

// Round 4
// 45974.316 us; speedup vs baseline: 1.0778x; 1.0716x over previous
//
#include <hip/hip_runtime.h>
#include <hip/hip_cooperative_groups.h>
#include <math.h>

namespace cg = cooperative_groups;

#define TT 200
#define BB 512
#define DD 40
#define HH 400
#define NC 12
#define GBLK 256
#define NTHR 1024

// key spaces (key = wib*8 + xcd; rowtile = slot = bid>>3):
//   beta : 125 keys = m*25 + coltile, m: 0=rt1(K800) 1=zt1(K800) 2=ah1p 3=rt0n 4=zt0n
//   alpha:  50 keys = m*25 + coltile, m: 0=h1 combine, 1=h0(t+1) combine
//   pro  :  25 keys = coltile
// Each (key, slot) is a 16x16 output tile; lane owns row r0+(lane&15), cols c0..c0+3.

struct P {
  const float *x;
  const float *Wh0,*bh0,*Wz0,*bz0,*Wr0,*br0,*Uh0,*Uz0,*Ur0;
  const float *Wh1,*bh1,*Wz1,*bz1,*Wr1,*br1,*Uh1,*Uz1,*Ur1;
  const float *Wfc,*bfc;
  float *h0a,*h0b,*h1a,*h1b;
  float *rt1,*zt1,*ah1p,*rt0n,*zt0n;
  float *out;
};

__device__ __forceinline__ float sigq(float x){
  float v = rintf(x * 12.4f) / 31.0f;
  return fminf(fmaxf(v, 0.0f), 1.0f);
}
__device__ __forceinline__ float tanhq(float x){
  float v = rintf(x * 31.0f) / 31.0f;
  return fminf(fmaxf(v, -1.0f), 1.0f);
}

// acc[j] += sum_k A[r][k] * W[c0+j][k], j=0..3. K multiple of 4.
__device__ __forceinline__ void gacc16(const float* __restrict__ A, int lda,
                                       const float* __restrict__ W, int ldw,
                                       int r, int c0, int K, float acc[4])
{
  const float4* a  = (const float4*)(A + (size_t)r*lda);
  const float4* w0 = (const float4*)(W + (size_t)(c0+0)*ldw);
  const float4* w1 = (const float4*)(W + (size_t)(c0+1)*ldw);
  const float4* w2 = (const float4*)(W + (size_t)(c0+2)*ldw);
  const float4* w3 = (const float4*)(W + (size_t)(c0+3)*ldw);
  const int K4 = K >> 2;
  for (int k = 0; k < K4; ++k) {
    float4 av = a[k];
    float4 v0 = w0[k], v1 = w1[k], v2 = w2[k], v3 = w3[k];
    acc[0]+=av.x*v0.x; acc[0]+=av.y*v0.y; acc[0]+=av.z*v0.z; acc[0]+=av.w*v0.w;
    acc[1]+=av.x*v1.x; acc[1]+=av.y*v1.y; acc[1]+=av.z*v1.z; acc[1]+=av.w*v1.w;
    acc[2]+=av.x*v2.x; acc[2]+=av.y*v2.y; acc[2]+=av.z*v2.z; acc[2]+=av.w*v2.w;
    acc[3]+=av.x*v3.x; acc[3]+=av.y*v3.y; acc[3]+=av.z*v3.z; acc[3]+=av.w*v3.w;
  }
}

// acc[j] += sum_k (Ap[r][k]*Am[r][k]) * W[c0+j][k]
__device__ __forceinline__ void pacc16(const float* __restrict__ Ap,
                                       const float* __restrict__ Am,
                                       const float* __restrict__ W, int ldw,
                                       int r, int c0, int K, float acc[4])
{
  const float4* ap = (const float4*)(Ap + (size_t)r*HH);
  const float4* am = (const float4*)(Am + (size_t)r*HH);
  const float4* w0 = (const float4*)(W + (size_t)(c0+0)*ldw);
  const float4* w1 = (const float4*)(W + (size_t)(c0+1)*ldw);
  const float4* w2 = (const float4*)(W + (size_t)(c0+2)*ldw);
  const float4* w3 = (const float4*)(W + (size_t)(c0+3)*ldw);
  const int K4 = K >> 2;
  for (int k = 0; k < K4; ++k) {
    float4 pv = ap[k], mv = am[k];
    float4 av; av.x=pv.x*mv.x; av.y=pv.y*mv.y; av.z=pv.z*mv.z; av.w=pv.w*mv.w;
    float4 v0 = w0[k], v1 = w1[k], v2 = w2[k], v3 = w3[k];
    acc[0]+=av.x*v0.x; acc[0]+=av.y*v0.y; acc[0]+=av.z*v0.z; acc[0]+=av.w*v0.w;
    acc[1]+=av.x*v1.x; acc[1]+=av.y*v1.y; acc[1]+=av.z*v1.z; acc[1]+=av.w*v1.w;
    acc[2]+=av.x*v2.x; acc[2]+=av.y*v2.y; acc[2]+=av.z*v2.z; acc[2]+=av.w*v2.w;
    acc[3]+=av.x*v3.x; acc[3]+=av.y*v3.y; acc[3]+=av.z*v3.z; acc[3]+=av.w*v3.w;
  }
}

__device__ void beta_wave(const P& p, int t, int key, int slot, int lane){
  const int m  = key / 25;
  const int j0 = (key % 25) * 16;
  const int r  = slot*16 + (lane & 15);
  const int c0 = j0 + (lane >> 4)*4;
  const float* h0n = (t & 1) ? p.h0b : p.h0a;
  const float* h1c = (t & 1) ? p.h1b : p.h1a;
  const float* xt1 = p.x + (size_t)((t+1) % TT) * BB * DD;

  float acc[4] = {0.f,0.f,0.f,0.f};
  const float* bias; float* out; int act = 1;
  if (m == 0)      { gacc16(h1c,HH,p.Ur1,HH,r,c0,HH,acc); gacc16(h0n,HH,p.Wr1,HH,r,c0,HH,acc); bias=p.br1; out=p.rt1; }
  else if (m == 1) { gacc16(h1c,HH,p.Uz1,HH,r,c0,HH,acc); gacc16(h0n,HH,p.Wz1,HH,r,c0,HH,acc); bias=p.bz1; out=p.zt1; }
  else if (m == 2) { gacc16(h0n,HH,p.Wh1,HH,r,c0,HH,acc); bias=p.bh1; out=p.ah1p; act=0; }
  else if (m == 3) { gacc16(h0n,HH,p.Ur0,HH,r,c0,HH,acc); gacc16(xt1,DD,p.Wr0,DD,r,c0,DD,acc); bias=p.br0; out=p.rt0n; }
  else             { gacc16(h0n,HH,p.Uz0,HH,r,c0,HH,acc); gacc16(xt1,DD,p.Wz0,DD,r,c0,DD,acc); bias=p.bz0; out=p.zt0n; }

  #pragma unroll
  for (int j = 0; j < 4; ++j) {
    int cc = c0 + j;
    float v = acc[j] + bias[cc];
    out[(size_t)r*HH + cc] = act ? sigq(v) : v;
  }
}

__device__ void alpha_wave(const P& p, int t, int key, int slot, int lane){
  const int m  = key / 25;
  const int j0 = (key % 25) * 16;
  const int r  = slot*16 + (lane & 15);
  const int c0 = j0 + (lane >> 4)*4;
  const float* h0n = (t & 1) ? p.h0b : p.h0a;
  const float* h1c = (t & 1) ? p.h1b : p.h1a;
  float* h0w = (t & 1) ? p.h0a : p.h0b;
  float* h1w = (t & 1) ? p.h1a : p.h1b;
  const float* xt1 = p.x + (size_t)((t+1) % TT) * BB * DD;

  float acc[4] = {0.f,0.f,0.f,0.f};
  if (m == 0) {
    pacc16(p.rt1, h1c, p.Uh1, HH, r, c0, HH, acc);
    #pragma unroll
    for (int j = 0; j < 4; ++j) {
      int cc = c0 + j;
      size_t idx = (size_t)r*HH + cc;
      float at1 = acc[j] + p.ah1p[idx];
      float z = p.zt1[idx], hv = h1c[idx];
      h1w[idx] = z*hv + (1.0f - z)*tanhq(at1);
    }
  } else {
    pacc16(p.rt0n, h0n, p.Uh0, HH, r, c0, HH, acc);
    gacc16(xt1, DD, p.Wh0, DD, r, c0, DD, acc);
    #pragma unroll
    for (int j = 0; j < 4; ++j) {
      int cc = c0 + j;
      size_t idx = (size_t)r*HH + cc;
      float at0 = acc[j] + p.bh0[cc];
      float z = p.zt0n[idx], hv = h0n[idx];
      h0w[idx] = z*hv + (1.0f - z)*tanhq(at0);
    }
  }
}

__device__ void pro_wave(const P& p, int key, int slot, int lane){
  const int j0 = key * 16;
  const int r  = slot*16 + (lane & 15);
  const int c0 = j0 + (lane >> 4)*4;
  float accz[4] = {0.f,0.f,0.f,0.f}, acca[4] = {0.f,0.f,0.f,0.f};
  gacc16(p.x, DD, p.Wz0, DD, r, c0, DD, accz);
  gacc16(p.x, DD, p.Wh0, DD, r, c0, DD, acca);
  #pragma unroll
  for (int j = 0; j < 4; ++j) {
    int cc = c0 + j;
    float z = sigq(accz[j] + p.bz0[cc]);
    float a = acca[j] + p.bh0[cc];
    p.h0a[(size_t)r*HH + cc] = (1.0f - z)*tanhq(a);
  }
}

__device__ void fc_wave(const P& p, int b, int lane){
  const float* h1 = p.h1a;   // h1(199): t=199 odd -> written to h1a
  float l[NC];
  #pragma unroll
  for (int cI = 0; cI < NC; ++cI) {
    float sm = 0.0f;
    for (int k = lane; k < HH; k += 64)
      sm += h1[(size_t)b*HH + k] * p.Wfc[(size_t)cI*HH + k];
    #pragma unroll
    for (int off = 32; off > 0; off >>= 1)
      sm += __shfl_xor(sm, off);
    l[cI] = sm + p.bfc[cI];
  }
  float mx = l[0];
  #pragma unroll
  for (int cI = 1; cI < NC; ++cI) mx = fmaxf(mx, l[cI]);
  float sum = 0.0f;
  #pragma unroll
  for (int cI = 0; cI < NC; ++cI) { l[cI] = expf(l[cI] - mx); sum += l[cI]; }
  float inv = 1.0f / sum;
  if (lane == 0) {
    #pragma unroll
    for (int cI = 0; cI < NC; ++cI) p.out[(size_t)b*NC + cI] = l[cI] * inv;
  }
}

// ---- cooperative single-kernel path: 256 blocks x 1024 threads (16 waves) ----
__global__ __launch_bounds__(NTHR, 4) void gru_coop(P p){
  cg::grid_group grid = cg::this_grid();
  const int bid  = blockIdx.x;
  const int tid  = threadIdx.x;
  const int wib  = tid >> 6;      // wave-in-block 0..15
  const int lane = tid & 63;
  const int xcd  = bid & 7;       // XCD-locality: fixed key set per XCD
  const int slot = bid >> 3;      // 0..31 -> rowtile
  const int key  = wib*8 + xcd;   // 0..127
  const int w    = bid*16 + wib;  // global wave id

  if (key < 25) pro_wave(p, key, slot, lane);
  grid.sync();
  for (int t = 0; t < TT; ++t) {
    if (key < 125) beta_wave(p, t, key, slot, lane);
    grid.sync();
    if (key < 50) alpha_wave(p, t, key, slot, lane);
    grid.sync();
  }
  if (w < BB) fc_wave(p, w, lane);
}

// ---- fallback regular-launch path (same mapping, per-phase kernels) ----
__global__ __launch_bounds__(NTHR) void k_pro(P p){
  const int wib = threadIdx.x >> 6, lane = threadIdx.x & 63;
  const int key = wib*8 + (blockIdx.x & 7), slot = blockIdx.x >> 3;
  if (key < 25) pro_wave(p, key, slot, lane);
}
__global__ __launch_bounds__(NTHR) void k_beta(P p, int t){
  const int wib = threadIdx.x >> 6, lane = threadIdx.x & 63;
  const int key = wib*8 + (blockIdx.x & 7), slot = blockIdx.x >> 3;
  if (key < 125) beta_wave(p, t, key, slot, lane);
}
__global__ __launch_bounds__(NTHR) void k_alpha(P p, int t){
  const int wib = threadIdx.x >> 6, lane = threadIdx.x & 63;
  const int key = wib*8 + (blockIdx.x & 7), slot = blockIdx.x >> 3;
  if (key < 50) alpha_wave(p, t, key, slot, lane);
}
__global__ __launch_bounds__(NTHR) void k_fc(P p){
  const int wib = threadIdx.x >> 6, lane = threadIdx.x & 63;
  const int w = blockIdx.x*16 + wib;
  if (w < BB) fc_wave(p, w, lane);
}

extern "C" void kernel_launch(void* const* d_in, const int* in_sizes, int n_in,
                              void* d_out, int out_size, void* d_ws, size_t ws_size,
                              hipStream_t stream) {
  P p;
  p.x   = (const float*)d_in[0];
  p.Wh0 = (const float*)d_in[1];  p.bh0 = (const float*)d_in[2];
  p.Wz0 = (const float*)d_in[3];  p.bz0 = (const float*)d_in[4];
  p.Wr0 = (const float*)d_in[5];  p.br0 = (const float*)d_in[6];
  p.Uh0 = (const float*)d_in[7];  p.Uz0 = (const float*)d_in[8];  p.Ur0 = (const float*)d_in[9];
  p.Wh1 = (const float*)d_in[10]; p.bh1 = (const float*)d_in[11];
  p.Wz1 = (const float*)d_in[12]; p.bz1 = (const float*)d_in[13];
  p.Wr1 = (const float*)d_in[14]; p.br1 = (const float*)d_in[15];
  p.Uh1 = (const float*)d_in[16]; p.Uz1 = (const float*)d_in[17]; p.Ur1 = (const float*)d_in[18];
  p.Wfc = (const float*)d_in[19]; p.bfc = (const float*)d_in[20];

  float* ws = (float*)d_ws;
  const size_t SZ = (size_t)BB * HH;
  p.h0a  = ws + 0*SZ;  p.h0b  = ws + 1*SZ;
  p.h1a  = ws + 2*SZ;  p.h1b  = ws + 3*SZ;
  p.rt1  = ws + 4*SZ;  p.zt1  = ws + 5*SZ;  p.ah1p = ws + 6*SZ;
  p.rt0n = ws + 7*SZ;  p.zt0n = ws + 8*SZ;
  p.out  = (float*)d_out;

  // h1(-1) = 0. Everything else is written before it is read.
  hipMemsetAsync(p.h1a, 0, SZ*sizeof(float), stream);

  void* args[] = { &p };
  hipError_t err = hipLaunchCooperativeKernel((const void*)gru_coop, dim3(GBLK),
                                              dim3(NTHR), args, 0, stream);
  if (err != hipSuccess) {
    // Deterministic fallback: identical math via regular launches.
    k_pro<<<dim3(GBLK), dim3(NTHR), 0, stream>>>(p);
    for (int t = 0; t < TT; ++t) {
      k_beta <<<dim3(GBLK), dim3(NTHR), 0, stream>>>(p, t);
      k_alpha<<<dim3(GBLK), dim3(NTHR), 0, stream>>>(p, t);
    }
    k_fc<<<dim3(GBLK), dim3(NTHR), 0, stream>>>(p);
  }
}

// Round 5
// 33748.950 us; speedup vs baseline: 1.4683x; 1.3622x over previous
//
#include <hip/hip_runtime.h>
#include <math.h>

#define TT 200
#define BB 512
#define DD 40
#define HH 400
#define NC 12
#define NBLK 500
#define NTHR 256

// block u (0..499): beta key = u>>2 (125 keys = m*25+coltile), quarter = u&3.
//   m: 0=rt1(K800) 1=zt1(K800) 2=ah1p(K400) 3=rt0n(K400+40) 4=zt0n(K400+40)
// blocks 0..199 additionally own alpha key = u>>2 (50 keys = m*25+coltile).
//   m: 0=h1 combine (Uh1), 1=h0(t+1) combine (Uh0+Wh0)
// Wave tile: 32 rows x 16 cols; lane owns rows r,r+1 (r=q*128+w*32+(lane&15)*2),
// cols c0..c0+3 (c0 = j0 + (lane>>4)*4). Weights LDS-resident for all 200 steps.

struct P {
  const float *x;
  const float *Wh0,*bh0,*Wz0,*bz0,*Wr0,*br0,*Uh0,*Uz0,*Ur0;
  const float *Wh1,*bh1,*Wz1,*bz1,*Wr1,*br1,*Uh1,*Uz1,*Ur1;
  const float *Wfc,*bfc;
  float *h0a,*h0b,*h1a,*h1b;
  float *rt1,*zt1,*ah1p,*rt0n,*zt0n;
  unsigned *bar;
  float *out;
};

__device__ __forceinline__ float sigq(float x){
  float v = rintf(x * 12.4f) / 31.0f;
  return fminf(fmaxf(v, 0.0f), 1.0f);
}
__device__ __forceinline__ float tanhq(float x){
  float v = rintf(x * 31.0f) / 31.0f;
  return fminf(fmaxf(v, -1.0f), 1.0f);
}

// ---- LDS weight slice loader: dst[k*16+c] = Wg[(j0+c)*ldw + k], coalesced in k ----
__device__ void load_slice(float* dst, const float* __restrict__ Wg, int ldw,
                           int j0, int K, int tid){
  const int c  = tid >> 4;   // 0..15
  const int ks = tid & 15;
  for (int k = ks; k < K; k += 16)
    dst[k*16 + c] = Wg[(size_t)(j0 + c)*ldw + k];
}

// acc[i][j] += sum_k A[r+i][k] * Wl[k*16 + cb+j]   (W from LDS, broadcast reads)
__device__ __forceinline__ void gaccL(const float* __restrict__ A, int lda,
                                      const float* __restrict__ Wl,
                                      int r, int cb, int K, float acc[2][4]){
  const float4* a0 = (const float4*)(A + (size_t)r*lda);
  const float4* a1 = (const float4*)(A + (size_t)r*lda + lda);
  const int K4 = K >> 2;
  #pragma unroll 4
  for (int k = 0; k < K4; ++k) {
    float4 av0 = a0[k], av1 = a1[k];
    float a0v[4] = {av0.x, av0.y, av0.z, av0.w};
    float a1v[4] = {av1.x, av1.y, av1.z, av1.w};
    #pragma unroll
    for (int i = 0; i < 4; ++i) {
      float4 wv = *(const float4*)(Wl + (k*4+i)*16 + cb);
      acc[0][0]+=a0v[i]*wv.x; acc[0][1]+=a0v[i]*wv.y; acc[0][2]+=a0v[i]*wv.z; acc[0][3]+=a0v[i]*wv.w;
      acc[1][0]+=a1v[i]*wv.x; acc[1][1]+=a1v[i]*wv.y; acc[1][2]+=a1v[i]*wv.z; acc[1][3]+=a1v[i]*wv.w;
    }
  }
}

// acc[i][j] += sum_k (Ap[r+i][k]*Am[r+i][k]) * Wl[k*16 + cb+j]
__device__ __forceinline__ void paccL(const float* __restrict__ Ap,
                                      const float* __restrict__ Am,
                                      const float* __restrict__ Wl,
                                      int r, int cb, int K, float acc[2][4]){
  const float4* p0 = (const float4*)(Ap + (size_t)r*HH);
  const float4* p1 = (const float4*)(Ap + (size_t)r*HH + HH);
  const float4* m0 = (const float4*)(Am + (size_t)r*HH);
  const float4* m1 = (const float4*)(Am + (size_t)r*HH + HH);
  const int K4 = K >> 2;
  #pragma unroll 4
  for (int k = 0; k < K4; ++k) {
    float4 pv0 = p0[k], mv0 = m0[k], pv1 = p1[k], mv1 = m1[k];
    float a0v[4] = {pv0.x*mv0.x, pv0.y*mv0.y, pv0.z*mv0.z, pv0.w*mv0.w};
    float a1v[4] = {pv1.x*mv1.x, pv1.y*mv1.y, pv1.z*mv1.z, pv1.w*mv1.w};
    #pragma unroll
    for (int i = 0; i < 4; ++i) {
      float4 wv = *(const float4*)(Wl + (k*4+i)*16 + cb);
      acc[0][0]+=a0v[i]*wv.x; acc[0][1]+=a0v[i]*wv.y; acc[0][2]+=a0v[i]*wv.z; acc[0][3]+=a0v[i]*wv.w;
      acc[1][0]+=a1v[i]*wv.x; acc[1][1]+=a1v[i]*wv.y; acc[1][2]+=a1v[i]*wv.z; acc[1][3]+=a1v[i]*wv.w;
    }
  }
}

// global-W accumulate (pro only, K=40, one-time)
__device__ __forceinline__ void gaccG(const float* __restrict__ A, int lda,
                                      const float* __restrict__ W, int ldw,
                                      int r, int c0, int K, float acc[2][4]){
  const float4* a0 = (const float4*)(A + (size_t)r*lda);
  const float4* a1 = (const float4*)(A + (size_t)r*lda + lda);
  const int K4 = K >> 2;
  for (int k = 0; k < K4; ++k) {
    float4 av0 = a0[k], av1 = a1[k];
    #pragma unroll
    for (int j = 0; j < 4; ++j) {
      float4 wv = *(const float4*)(W + (size_t)(c0+j)*ldw + k*4);
      acc[0][j]+=av0.x*wv.x; acc[0][j]+=av0.y*wv.y; acc[0][j]+=av0.z*wv.z; acc[0][j]+=av0.w*wv.w;
      acc[1][j]+=av1.x*wv.x; acc[1][j]+=av1.y*wv.y; acc[1][j]+=av1.z*wv.z; acc[1][j]+=av1.w*wv.w;
    }
  }
}

// ---- phase bodies ----
__device__ void beta_wave(const P& p, int t, int bm, int bj0, int r, int cb,
                          const float* Wb0, const float* Wb1){
  const float* h0n = (t & 1) ? p.h0b : p.h0a;
  const float* h1c = (t & 1) ? p.h1b : p.h1a;
  const float* xt1 = p.x + (size_t)((t+1) % TT) * BB * DD;
  float acc[2][4] = {};
  const float* bias; float* out; int act = 1;
  if (bm == 0)      { gaccL(h1c,HH,Wb0,r,cb,HH,acc); gaccL(h0n,HH,Wb1,r,cb,HH,acc); bias=p.br1; out=p.rt1; }
  else if (bm == 1) { gaccL(h1c,HH,Wb0,r,cb,HH,acc); gaccL(h0n,HH,Wb1,r,cb,HH,acc); bias=p.bz1; out=p.zt1; }
  else if (bm == 2) { gaccL(h0n,HH,Wb0,r,cb,HH,acc); bias=p.bh1; out=p.ah1p; act=0; }
  else if (bm == 3) { gaccL(h0n,HH,Wb0,r,cb,HH,acc); gaccL(xt1,DD,Wb1,r,cb,DD,acc); bias=p.br0; out=p.rt0n; }
  else              { gaccL(h0n,HH,Wb0,r,cb,HH,acc); gaccL(xt1,DD,Wb1,r,cb,DD,acc); bias=p.bz0; out=p.zt0n; }
  const int c0 = bj0 + cb;
  #pragma unroll
  for (int i = 0; i < 2; ++i) {
    float4 v;
    v.x = acc[i][0] + bias[c0+0];
    v.y = acc[i][1] + bias[c0+1];
    v.z = acc[i][2] + bias[c0+2];
    v.w = acc[i][3] + bias[c0+3];
    if (act) { v.x = sigq(v.x); v.y = sigq(v.y); v.z = sigq(v.z); v.w = sigq(v.w); }
    *(float4*)(out + (size_t)(r+i)*HH + c0) = v;
  }
}

__device__ void alpha_wave(const P& p, int t, int am, int aj0, int r, int cb,
                           const float* Wa, const float* Wa2){
  const float* h0n = (t & 1) ? p.h0b : p.h0a;
  const float* h1c = (t & 1) ? p.h1b : p.h1a;
  float* h0w = (t & 1) ? p.h0a : p.h0b;
  float* h1w = (t & 1) ? p.h1a : p.h1b;
  const float* xt1 = p.x + (size_t)((t+1) % TT) * BB * DD;
  float acc[2][4] = {};
  const int c0 = aj0 + cb;
  if (am == 0) {
    paccL(p.rt1, h1c, Wa, r, cb, HH, acc);
    #pragma unroll
    for (int i = 0; i < 2; ++i) {
      size_t base = (size_t)(r+i)*HH + c0;
      float4 ap = *(const float4*)(p.ah1p + base);
      float4 z  = *(const float4*)(p.zt1 + base);
      float4 hv = *(const float4*)(h1c + base);
      float4 o;
      o.x = z.x*hv.x + (1.0f - z.x)*tanhq(acc[i][0] + ap.x);
      o.y = z.y*hv.y + (1.0f - z.y)*tanhq(acc[i][1] + ap.y);
      o.z = z.z*hv.z + (1.0f - z.z)*tanhq(acc[i][2] + ap.z);
      o.w = z.w*hv.w + (1.0f - z.w)*tanhq(acc[i][3] + ap.w);
      *(float4*)(h1w + base) = o;
    }
  } else {
    paccL(p.rt0n, h0n, Wa, r, cb, HH, acc);
    gaccL(xt1, DD, Wa2, r, cb, DD, acc);
    #pragma unroll
    for (int i = 0; i < 2; ++i) {
      size_t base = (size_t)(r+i)*HH + c0;
      float4 z  = *(const float4*)(p.zt0n + base);
      float4 hv = *(const float4*)(h0n + base);
      float4 o;
      o.x = z.x*hv.x + (1.0f - z.x)*tanhq(acc[i][0] + p.bh0[c0+0]);
      o.y = z.y*hv.y + (1.0f - z.y)*tanhq(acc[i][1] + p.bh0[c0+1]);
      o.z = z.z*hv.z + (1.0f - z.z)*tanhq(acc[i][2] + p.bh0[c0+2]);
      o.w = z.w*hv.w + (1.0f - z.w)*tanhq(acc[i][3] + p.bh0[c0+3]);
      *(float4*)(h0w + base) = o;
    }
  }
}

// prologue: h0(0) = (1 - sigq(x0 Wz0^T + bz0)) * tanhq(x0 Wh0^T + bh0); h(-1)=0
__device__ void pro_wave(const P& p, int coltile, int r, int cb){
  const int c0 = coltile*16 + cb;
  float accz[2][4] = {}, acca[2][4] = {};
  gaccG(p.x, DD, p.Wz0, DD, r, c0, DD, accz);
  gaccG(p.x, DD, p.Wh0, DD, r, c0, DD, acca);
  #pragma unroll
  for (int i = 0; i < 2; ++i) {
    float4 o;
    float z;
    z = sigq(accz[i][0] + p.bz0[c0+0]); o.x = (1.0f - z)*tanhq(acca[i][0] + p.bh0[c0+0]);
    z = sigq(accz[i][1] + p.bz0[c0+1]); o.y = (1.0f - z)*tanhq(acca[i][1] + p.bh0[c0+1]);
    z = sigq(accz[i][2] + p.bz0[c0+2]); o.z = (1.0f - z)*tanhq(acca[i][2] + p.bh0[c0+2]);
    z = sigq(accz[i][3] + p.bz0[c0+3]); o.w = (1.0f - z)*tanhq(acca[i][3] + p.bh0[c0+3]);
    *(float4*)(p.h0a + (size_t)(r+i)*HH + c0) = o;
  }
}

__device__ void fc_wave(const P& p, int b, int lane){
  const float* h1 = p.h1a;   // h1(199): t=199 odd -> h1a
  float l[NC];
  #pragma unroll
  for (int cI = 0; cI < NC; ++cI) {
    float sm = 0.0f;
    for (int k = lane; k < HH; k += 64)
      sm += h1[(size_t)b*HH + k] * p.Wfc[(size_t)cI*HH + k];
    #pragma unroll
    for (int off = 32; off > 0; off >>= 1)
      sm += __shfl_xor(sm, off);
    l[cI] = sm + p.bfc[cI];
  }
  float mx = l[0];
  #pragma unroll
  for (int cI = 1; cI < NC; ++cI) mx = fmaxf(mx, l[cI]);
  float sum = 0.0f;
  #pragma unroll
  for (int cI = 0; cI < NC; ++cI) { l[cI] = expf(l[cI] - mx); sum += l[cI]; }
  float inv = 1.0f / sum;
  if (lane == 0) {
    #pragma unroll
    for (int cI = 0; cI < NC; ++cI) p.out[(size_t)b*NC + cI] = l[cI] * inv;
  }
}

// ---- hand-rolled grid barrier: 16 spaced arrival counters -> master -> gen ----
// Monotone counts (no resets): barrier bn complete when gen == bn+1.
__device__ void gbar(int bn, unsigned* bar, int u){
  __syncthreads();
  if (threadIdx.x == 0) {
    __threadfence();                                    // release (L2 writeback)
    const int i = u & 15;
    const int quota = (NBLK >> 4) + ((i < (NBLK & 15)) ? 1 : 0);
    unsigned* c0  = bar + i*32;                         // 128B-spaced
    unsigned* c1  = bar + 512;
    unsigned* gen = bar + 544;
    unsigned v = __hip_atomic_fetch_add(c0, 1u, __ATOMIC_RELEASE, __HIP_MEMORY_SCOPE_AGENT);
    if (v + 1u == (unsigned)quota * (unsigned)(bn+1)) {
      unsigned w2 = __hip_atomic_fetch_add(c1, 1u, __ATOMIC_ACQ_REL, __HIP_MEMORY_SCOPE_AGENT);
      if (w2 + 1u == 16u * (unsigned)(bn+1))
        __hip_atomic_store(gen, (unsigned)(bn+1), __ATOMIC_RELEASE, __HIP_MEMORY_SCOPE_AGENT);
    }
    while (__hip_atomic_load(gen, __ATOMIC_RELAXED, __HIP_MEMORY_SCOPE_AGENT) < (unsigned)(bn+1))
      __builtin_amdgcn_s_sleep(2);
    __threadfence();                                    // acquire (invalidate stale)
  }
  __syncthreads();
}

// ---- LDS loaders ----
__device__ void load_beta_lds(const P& p, int bm, int bj0, float* Wb0, float* Wb1, int tid){
  if (bm == 0)      { load_slice(Wb0, p.Ur1, HH, bj0, HH, tid); load_slice(Wb1, p.Wr1, HH, bj0, HH, tid); }
  else if (bm == 1) { load_slice(Wb0, p.Uz1, HH, bj0, HH, tid); load_slice(Wb1, p.Wz1, HH, bj0, HH, tid); }
  else if (bm == 2) { load_slice(Wb0, p.Wh1, HH, bj0, HH, tid); }
  else if (bm == 3) { load_slice(Wb0, p.Ur0, HH, bj0, HH, tid); load_slice(Wb1, p.Wr0, DD, bj0, DD, tid); }
  else              { load_slice(Wb0, p.Uz0, HH, bj0, HH, tid); load_slice(Wb1, p.Wz0, DD, bj0, DD, tid); }
}
__device__ void load_alpha_lds(const P& p, int am, int aj0, float* Wa, float* Wa2, int tid){
  if (am == 0) load_slice(Wa, p.Uh1, HH, aj0, HH, tid);
  else       { load_slice(Wa, p.Uh0, HH, aj0, HH, tid); load_slice(Wa2, p.Wh0, DD, aj0, DD, tid); }
}

// ---- persistent cooperative kernel: 500 blocks x 256 thr, weights in LDS ----
__global__ __launch_bounds__(NTHR, 2) void gru_coop(P p){
  __shared__ float lds[19840];   // 79,360 B: Wb0|Wb1|Wa|Wa2
  float* Wb0 = lds;
  float* Wb1 = lds + 6400;
  float* Wa  = lds + 12800;
  float* Wa2 = lds + 19200;

  const int u    = blockIdx.x;
  const int tid  = threadIdx.x;
  const int w    = tid >> 6;
  const int lane = tid & 63;

  const int bkey = u >> 2, bq = u & 3;
  const int bm = bkey / 25, bj0 = (bkey % 25) * 16;
  const int akey = u >> 2;                       // valid only for u<200
  const int am = akey / 25, aj0 = (akey % 25) * 16;

  const int r  = bq*128 + w*32 + (lane & 15)*2;
  const int cb = (lane >> 4) * 4;

  load_beta_lds(p, bm, bj0, Wb0, Wb1, tid);
  if (u < 200) load_alpha_lds(p, am, aj0, Wa, Wa2, tid);
  if (u < 100) pro_wave(p, u >> 2, (u & 3)*128 + w*32 + (lane & 15)*2, cb);

  int bn = 0;
  gbar(bn++, p.bar, u);
  for (int t = 0; t < TT; ++t) {
    beta_wave(p, t, bm, bj0, r, cb, Wb0, Wb1);
    gbar(bn++, p.bar, u);
    if (u < 200) alpha_wave(p, t, am, aj0, r, cb, Wa, Wa2);
    gbar(bn++, p.bar, u);
  }
  if (u < 128) fc_wave(p, u*4 + w, lane);
}

// ---- fallback: regular launches, LDS reloaded per launch (correctness insurance) ----
__global__ __launch_bounds__(NTHR) void k_pro(P p){
  const int u = blockIdx.x, tid = threadIdx.x, w = tid >> 6, lane = tid & 63;
  pro_wave(p, u >> 2, (u & 3)*128 + w*32 + (lane & 15)*2, ((lane >> 4)*4));
}
__global__ __launch_bounds__(NTHR) void k_beta(P p, int t){
  __shared__ float lds[12800];
  const int u = blockIdx.x, tid = threadIdx.x, w = tid >> 6, lane = tid & 63;
  const int bkey = u >> 2, bq = u & 3;
  const int bm = bkey / 25, bj0 = (bkey % 25) * 16;
  load_beta_lds(p, bm, bj0, lds, lds + 6400, tid);
  __syncthreads();
  beta_wave(p, t, bm, bj0, bq*128 + w*32 + (lane & 15)*2, (lane >> 4)*4, lds, lds + 6400);
}
__global__ __launch_bounds__(NTHR) void k_alpha(P p, int t){
  __shared__ float lds[7040];
  const int u = blockIdx.x, tid = threadIdx.x, w = tid >> 6, lane = tid & 63;
  const int akey = u >> 2, aq = u & 3;
  const int am = akey / 25, aj0 = (akey % 25) * 16;
  load_alpha_lds(p, am, aj0, lds, lds + 6400, tid);
  __syncthreads();
  alpha_wave(p, t, am, aj0, aq*128 + w*32 + (lane & 15)*2, (lane >> 4)*4, lds, lds + 6400);
}
__global__ __launch_bounds__(NTHR) void k_fc(P p){
  const int w = threadIdx.x >> 6, lane = threadIdx.x & 63;
  fc_wave(p, blockIdx.x*4 + w, lane);
}

extern "C" void kernel_launch(void* const* d_in, const int* in_sizes, int n_in,
                              void* d_out, int out_size, void* d_ws, size_t ws_size,
                              hipStream_t stream) {
  P p;
  p.x   = (const float*)d_in[0];
  p.Wh0 = (const float*)d_in[1];  p.bh0 = (const float*)d_in[2];
  p.Wz0 = (const float*)d_in[3];  p.bz0 = (const float*)d_in[4];
  p.Wr0 = (const float*)d_in[5];  p.br0 = (const float*)d_in[6];
  p.Uh0 = (const float*)d_in[7];  p.Uz0 = (const float*)d_in[8];  p.Ur0 = (const float*)d_in[9];
  p.Wh1 = (const float*)d_in[10]; p.bh1 = (const float*)d_in[11];
  p.Wz1 = (const float*)d_in[12]; p.bz1 = (const float*)d_in[13];
  p.Wr1 = (const float*)d_in[14]; p.br1 = (const float*)d_in[15];
  p.Uh1 = (const float*)d_in[16]; p.Uz1 = (const float*)d_in[17]; p.Ur1 = (const float*)d_in[18];
  p.Wfc = (const float*)d_in[19]; p.bfc = (const float*)d_in[20];

  float* ws = (float*)d_ws;
  const size_t SZ = (size_t)BB * HH;
  p.h0a  = ws + 0*SZ;  p.h0b  = ws + 1*SZ;
  p.h1a  = ws + 2*SZ;  p.h1b  = ws + 3*SZ;
  p.rt1  = ws + 4*SZ;  p.zt1  = ws + 5*SZ;  p.ah1p = ws + 6*SZ;
  p.rt0n = ws + 7*SZ;  p.zt0n = ws + 8*SZ;
  p.bar  = (unsigned*)(ws + 9*SZ);
  p.out  = (float*)d_out;

  // h1(-1) = 0; barrier counters/gen = 0 (d_ws is poisoned before every launch).
  hipMemsetAsync(p.h1a, 0, SZ*sizeof(float), stream);
  hipMemsetAsync(p.bar, 0, 4096, stream);

  void* args[] = { &p };
  hipError_t err = hipLaunchCooperativeKernel((const void*)gru_coop, dim3(NBLK),
                                              dim3(NTHR), args, 0, stream);
  if (err != hipSuccess) {
    // Deterministic fallback: identical math via per-phase launches.
    k_pro<<<dim3(100), dim3(NTHR), 0, stream>>>(p);
    for (int t = 0; t < TT; ++t) {
      k_beta <<<dim3(NBLK), dim3(NTHR), 0, stream>>>(p, t);
      k_alpha<<<dim3(200),  dim3(NTHR), 0, stream>>>(p, t);
    }
    k_fc<<<dim3(128), dim3(NTHR), 0, stream>>>(p);
  }
}